// Round 2
// baseline (6116.196 us; speedup 1.0000x reference)
//
#include <hip/hip_runtime.h>
#include <math.h>

#define B 128
#define S 20
#define H 512
#define E 512
#define V 10000
#define NG 2048   // 4*H (gate width)
#define HB 1024   // 2*H (state row width)

__device__ __forceinline__ float sigf(float x) { return 1.0f / (1.0f + expf(-x)); }

// ---------------------------------------------------------------------------
// K1: X0G[t*B+b][n] = concat(baseimg[b], emb[tok[b][t]]) @ W0[0:1024,:] + b0
// M=2560, N=2048, K=1024.  BM=BN=128, BK=8, 256 thr, 8x8/thread (2x2 of 4x4).
// ---------------------------------------------------------------------------
__global__ __launch_bounds__(256) void k_x0g(
    const int* __restrict__ tok, const float* __restrict__ base,
    const float* __restrict__ emb, const float* __restrict__ W0,
    const float* __restrict__ b0, float* __restrict__ X0G)
{
  __shared__ __align__(16) float As[8][128];
  __shared__ __align__(16) float Bs[8][128];
  const int tid = threadIdx.x;
  const int m0 = blockIdx.y * 128, n0 = blockIdx.x * 128;
  const int tx = tid & 15, ty = tid >> 4;

  const int rloc = tid >> 1;                 // 0..127
  const int arow = m0 + rloc;                // 0..2559
  const int ak4  = (tid & 1) * 4;            // 0 or 4
  const int t_ = arow >> 7, b_ = arow & 127;
  const int token = tok[b_ * S + t_];
  const float* arow_lo = base + (size_t)b_ * E;      // k in [0,512)
  const float* arow_hi = emb + (size_t)token * E;    // (k-512) in [0,512)

  const int bkk = tid >> 5;                  // 0..7
  const int bc4 = (tid & 31) * 4;            // 0..124

  float acc[2][2][4][4];
  #pragma unroll
  for (int p=0;p<2;p++)
    #pragma unroll
    for (int q=0;q<2;q++)
      #pragma unroll
      for (int i=0;i<4;i++)
        #pragma unroll
        for (int j=0;j<4;j++) acc[p][q][i][j]=0.f;

  for (int kt = 0; kt < 1024/8; ++kt) {
    const int k = kt*8 + ak4;
    float4 av = (k < 512) ? *(const float4*)(arow_lo + k)
                          : *(const float4*)(arow_hi + (k - 512));
    float4 bv = *(const float4*)(W0 + (size_t)(kt*8 + bkk)*NG + n0 + bc4);
    __syncthreads();
    As[ak4+0][rloc] = av.x; As[ak4+1][rloc] = av.y;
    As[ak4+2][rloc] = av.z; As[ak4+3][rloc] = av.w;
    *(float4*)&Bs[bkk][bc4] = bv;
    __syncthreads();
    #pragma unroll
    for (int kk=0; kk<8; ++kk) {
      float a[2][4], b[2][4];
      *(float4*)a[0] = *(const float4*)&As[kk][ty*4];
      *(float4*)a[1] = *(const float4*)&As[kk][64 + ty*4];
      *(float4*)b[0] = *(const float4*)&Bs[kk][tx*4];
      *(float4*)b[1] = *(const float4*)&Bs[kk][64 + tx*4];
      #pragma unroll
      for (int p=0;p<2;p++)
        #pragma unroll
        for (int q=0;q<2;q++)
          #pragma unroll
          for (int i=0;i<4;i++)
            #pragma unroll
            for (int j=0;j<4;j++)
              acc[p][q][i][j] += a[p][i] * b[q][j];
    }
  }

  #pragma unroll
  for (int p=0;p<2;p++)
    #pragma unroll
    for (int i=0;i<4;i++) {
      const int row = m0 + p*64 + ty*4 + i;
      #pragma unroll
      for (int q=0;q<2;q++) {
        const int col = n0 + q*64 + tx*4;
        float4 bb = *(const float4*)(b0 + col);
        float4 o;
        o.x = acc[p][q][i][0] + bb.x; o.y = acc[p][q][i][1] + bb.y;
        o.z = acc[p][q][i][2] + bb.z; o.w = acc[p][q][i][3] + bb.w;
        *(float4*)(X0G + (size_t)row*NG + col) = o;
      }
    }
}

// ---------------------------------------------------------------------------
// K2: cell0.  gates = x0g_t + h0_prev @ W0[1024:1536,:], fused LSTM pointwise.
// M=128 rows, 512 gate-quad cols (thread owns i/f/g/o of its 2 columns).
// BM=16, BNq=32, BK=64 (8 K-tiles, 2 barriers each).  grid(16,8), 256 thr.
// ---------------------------------------------------------------------------
__global__ __launch_bounds__(256) void k_cell0(
    const float* __restrict__ s0p, const float* __restrict__ x0g,
    const float* __restrict__ W0, float* __restrict__ s0c,
    float* __restrict__ fin)
{
  __shared__ __align__(16) float As[16][64];     // [row][k]
  __shared__ __align__(16) float Bs[4][64][32];  // [gate][k][col]
  const int tid = threadIdx.x;
  const int tx = tid & 15, ty = tid >> 4;
  const int m0 = blockIdx.y * 16, n0 = blockIdx.x * 32;

  const int a_rl = tid >> 4;        // 0..15 row
  const int a_k4 = (tid & 15) * 4;  // 0..60

  float acc[4][2];
  #pragma unroll
  for (int g=0; g<4; g++) { acc[g][0]=0.f; acc[g][1]=0.f; }

  for (int kt = 0; kt < 512/64; ++kt) {
    float4 av = *(const float4*)(s0p + (size_t)(m0+a_rl)*HB + kt*64 + a_k4); // h-part
    float4 bv[8];
    #pragma unroll
    for (int p=0;p<8;p++) {
      const int idx = p*256 + tid;
      const int gg = idx >> 9, rem = idx & 511;
      const int kk = rem >> 3, c4 = (rem & 7)*4;
      bv[p] = *(const float4*)(W0 + (size_t)(1024 + kt*64 + kk)*NG + gg*512 + n0 + c4);
    }
    __syncthreads();
    *(float4*)&As[a_rl][a_k4] = av;
    #pragma unroll
    for (int p=0;p<8;p++) {
      const int idx = p*256 + tid;
      const int gg = idx >> 9, rem = idx & 511;
      const int kk = rem >> 3, c4 = (rem & 7)*4;
      *(float4*)&Bs[gg][kk][c4] = bv[p];
    }
    __syncthreads();
    #pragma unroll
    for (int kk=0; kk<64; ++kk) {
      const float a = As[ty][kk];
      #pragma unroll
      for (int gg=0; gg<4; ++gg) {
        float2 b2 = *(const float2*)&Bs[gg][kk][tx*2];
        acc[gg][0] += a * b2.x; acc[gg][1] += a * b2.y;
      }
    }
  }

  const int r = m0 + ty;
  #pragma unroll
  for (int j=0;j<2;j++) {
    const int nh = n0 + tx*2 + j;
    const float gi = acc[0][j] + x0g[(size_t)r*NG + 0*512  + nh];
    const float gf = acc[1][j] + x0g[(size_t)r*NG + 1*512  + nh];
    const float gg = acc[2][j] + x0g[(size_t)r*NG + 2*512  + nh];
    const float go = acc[3][j] + x0g[(size_t)r*NG + 3*512  + nh];
    const float c_old = s0p[(size_t)r*HB + H + nh];
    const float c_new = sigf(gf)*c_old + sigf(gi)*tanhf(gg);
    const float h_new = sigf(go)*tanhf(c_new);
    s0c[(size_t)r*HB + nh]     = h_new;
    s0c[(size_t)r*HB + H + nh] = c_new;
    if (fin) { fin[(size_t)r*HB + nh] = h_new; fin[(size_t)r*HB + H + nh] = c_new; }
  }
}

// ---------------------------------------------------------------------------
// K3: att = tanh([h0|c0] @ W_att + b_att).  M=128, N=512, K=1024.
// BM=16, BN=32, BK=64 (16 K-tiles). grid(16,8), 256 thr.
// ---------------------------------------------------------------------------
__global__ __launch_bounds__(256) void k_att(
    const float* __restrict__ s0c, const float* __restrict__ Watt,
    const float* __restrict__ batt, float* __restrict__ att)
{
  __shared__ __align__(16) float As[16][64];
  __shared__ __align__(16) float Bs[64][32];
  const int tid = threadIdx.x;
  const int tx = tid & 15, ty = tid >> 4;
  const int m0 = blockIdx.y * 16, n0 = blockIdx.x * 32;

  const int a_rl = tid >> 4;        // 0..15
  const int a_k4 = (tid & 15) * 4;  // 0..60

  float acc0 = 0.f, acc1 = 0.f;

  for (int kt = 0; kt < 1024/64; ++kt) {
    float4 av = *(const float4*)(s0c + (size_t)(m0+a_rl)*HB + kt*64 + a_k4); // [h|c] row
    float4 bv[2];
    #pragma unroll
    for (int p=0;p<2;p++) {
      const int idx = p*256 + tid;
      const int kk = idx >> 3, c4 = (idx & 7)*4;
      bv[p] = *(const float4*)(Watt + (size_t)(kt*64 + kk)*H + n0 + c4);
    }
    __syncthreads();
    *(float4*)&As[a_rl][a_k4] = av;
    #pragma unroll
    for (int p=0;p<2;p++) {
      const int idx = p*256 + tid;
      const int kk = idx >> 3, c4 = (idx & 7)*4;
      *(float4*)&Bs[kk][c4] = bv[p];
    }
    __syncthreads();
    #pragma unroll
    for (int kk=0; kk<64; ++kk) {
      const float a = As[ty][kk];
      float2 b2 = *(const float2*)&Bs[kk][tx*2];
      acc0 += a * b2.x; acc1 += a * b2.y;
    }
  }

  const int r = m0 + ty;
  const int n = n0 + tx*2;
  att[(size_t)r*H + n]   = tanhf(acc0 + batt[n]);
  att[(size_t)r*H + n+1] = tanhf(acc1 + batt[n+1]);
}

// ---------------------------------------------------------------------------
// K4: cell1.  gates = [h0|att|h1] @ W1 + b1, fused LSTM pointwise.
// K=1536 in three 512-regions (BK=64 tiles never straddle a region).
// BM=16, BNq=32, BK=64 (24 K-tiles). grid(16,8), 256 thr. Writes h1 to H1all.
// ---------------------------------------------------------------------------
__global__ __launch_bounds__(256) void k_cell1(
    const float* __restrict__ s0c, const float* __restrict__ attb,
    const float* __restrict__ s1p, const float* __restrict__ W1,
    const float* __restrict__ b1, float* __restrict__ s1c,
    float* __restrict__ h1out, float* __restrict__ fin)
{
  __shared__ __align__(16) float As[16][64];
  __shared__ __align__(16) float Bs[4][64][32];
  const int tid = threadIdx.x;
  const int tx = tid & 15, ty = tid >> 4;
  const int m0 = blockIdx.y * 16, n0 = blockIdx.x * 32;

  const int a_rl = tid >> 4;
  const int a_k4 = (tid & 15) * 4;

  float acc[4][2];
  #pragma unroll
  for (int g=0; g<4; g++) { acc[g][0]=0.f; acc[g][1]=0.f; }

  for (int kt = 0; kt < 1536/64; ++kt) {
    const int kbase = kt*64;
    const int k = kbase + a_k4;
    const int rr = m0 + a_rl;
    float4 av;
    if (kbase < 512)       av = *(const float4*)(s0c  + (size_t)rr*HB + k);          // h0
    else if (kbase < 1024) av = *(const float4*)(attb + (size_t)rr*H  + (k-512));    // att
    else                   av = *(const float4*)(s1p  + (size_t)rr*HB + (k-1024));   // h1 prev
    float4 bv[8];
    #pragma unroll
    for (int p=0;p<8;p++) {
      const int idx = p*256 + tid;
      const int gg = idx >> 9, rem = idx & 511;
      const int kk = rem >> 3, c4 = (rem & 7)*4;
      bv[p] = *(const float4*)(W1 + (size_t)(kbase + kk)*NG + gg*512 + n0 + c4);
    }
    __syncthreads();
    *(float4*)&As[a_rl][a_k4] = av;
    #pragma unroll
    for (int p=0;p<8;p++) {
      const int idx = p*256 + tid;
      const int gg = idx >> 9, rem = idx & 511;
      const int kk = rem >> 3, c4 = (rem & 7)*4;
      *(float4*)&Bs[gg][kk][c4] = bv[p];
    }
    __syncthreads();
    #pragma unroll
    for (int kk=0; kk<64; ++kk) {
      const float a = As[ty][kk];
      #pragma unroll
      for (int gg=0; gg<4; ++gg) {
        float2 b2 = *(const float2*)&Bs[gg][kk][tx*2];
        acc[gg][0] += a * b2.x; acc[gg][1] += a * b2.y;
      }
    }
  }

  const int r = m0 + ty;
  #pragma unroll
  for (int j=0;j<2;j++) {
    const int nh = n0 + tx*2 + j;
    const float gi = acc[0][j] + b1[0*512 + nh];
    const float gf = acc[1][j] + b1[1*512 + nh];
    const float gg = acc[2][j] + b1[2*512 + nh];
    const float go = acc[3][j] + b1[3*512 + nh];
    const float c_old = s1p[(size_t)r*HB + H + nh];
    const float c_new = sigf(gf)*c_old + sigf(gi)*tanhf(gg);
    const float h_new = sigf(go)*tanhf(c_new);
    s1c[(size_t)r*HB + nh]     = h_new;
    s1c[(size_t)r*HB + H + nh] = c_new;
    h1out[(size_t)r*H + nh]    = h_new;
    if (fin) { fin[(size_t)r*HB + nh] = h_new; fin[(size_t)r*HB + H + nh] = c_new; }
  }
}

// ---------------------------------------------------------------------------
// K5: logits[b][t][:] = H1all[t*B+b] @ W_out + b_out.
// M=2560, N=10000, K=512. BM=BN=128, BK=8. grid(79,20), 256 thr.
// ---------------------------------------------------------------------------
__global__ __launch_bounds__(256) void k_logits(
    const float* __restrict__ H1, const float* __restrict__ Wout,
    const float* __restrict__ bout, float* __restrict__ out)
{
  __shared__ __align__(16) float As[8][128];
  __shared__ __align__(16) float Bs[8][128];
  const int tid = threadIdx.x;
  const int m0 = blockIdx.y * 128, n0 = blockIdx.x * 128;
  const int tx = tid & 15, ty = tid >> 4;

  const int rloc = tid >> 1;
  const int arow = m0 + rloc;
  const int ak4  = (tid & 1) * 4;
  const int bkk = tid >> 5;
  const int bc4 = (tid & 31) * 4;

  float acc[2][2][4][4];
  #pragma unroll
  for (int p=0;p<2;p++)
    #pragma unroll
    for (int q=0;q<2;q++)
      #pragma unroll
      for (int i=0;i<4;i++)
        #pragma unroll
        for (int j=0;j<4;j++) acc[p][q][i][j]=0.f;

  for (int kt = 0; kt < 512/8; ++kt) {
    float4 av = *(const float4*)(H1 + (size_t)arow*H + kt*8 + ak4);
    const int bcol = n0 + bc4;
    float4 bv = make_float4(0.f,0.f,0.f,0.f);
    if (bcol < V) bv = *(const float4*)(Wout + (size_t)(kt*8 + bkk)*V + bcol);
    __syncthreads();
    As[ak4+0][rloc] = av.x; As[ak4+1][rloc] = av.y;
    As[ak4+2][rloc] = av.z; As[ak4+3][rloc] = av.w;
    *(float4*)&Bs[bkk][bc4] = bv;
    __syncthreads();
    #pragma unroll
    for (int kk=0; kk<8; ++kk) {
      float a[2][4], b[2][4];
      *(float4*)a[0] = *(const float4*)&As[kk][ty*4];
      *(float4*)a[1] = *(const float4*)&As[kk][64 + ty*4];
      *(float4*)b[0] = *(const float4*)&Bs[kk][tx*4];
      *(float4*)b[1] = *(const float4*)&Bs[kk][64 + tx*4];
      #pragma unroll
      for (int p=0;p<2;p++)
        #pragma unroll
        for (int q=0;q<2;q++)
          #pragma unroll
          for (int i=0;i<4;i++)
            #pragma unroll
            for (int j=0;j<4;j++)
              acc[p][q][i][j] += a[p][i] * b[q][j];
    }
  }

  #pragma unroll
  for (int p=0;p<2;p++)
    #pragma unroll
    for (int i=0;i<4;i++) {
      const int row = m0 + p*64 + ty*4 + i;      // r = t*B + b
      const int t_ = row >> 7, b_ = row & 127;
      float* orow = out + ((size_t)b_*S + t_) * V;
      #pragma unroll
      for (int q=0;q<2;q++) {
        const int col = n0 + q*64 + tx*4;
        if (col < V) {
          float4 bb = *(const float4*)(bout + col);
          float4 o;
          o.x = acc[p][q][i][0] + bb.x; o.y = acc[p][q][i][1] + bb.y;
          o.z = acc[p][q][i][2] + bb.z; o.w = acc[p][q][i][3] + bb.w;
          *(float4*)(orow + col) = o;
        }
      }
    }
}

// ---------------------------------------------------------------------------
extern "C" void kernel_launch(void* const* d_in, const int* in_sizes, int n_in,
                              void* d_out, int out_size, void* d_ws, size_t ws_size,
                              hipStream_t stream) {
  const int*   tok  = (const int*)  d_in[0];
  const float* base = (const float*)d_in[1];
  const float* init = (const float*)d_in[2];
  const float* emb  = (const float*)d_in[3];
  const float* W0   = (const float*)d_in[4];
  const float* b0   = (const float*)d_in[5];
  const float* W1   = (const float*)d_in[6];
  const float* b1   = (const float*)d_in[7];
  const float* Watt = (const float*)d_in[8];
  const float* batt = (const float*)d_in[9];
  const float* Wout = (const float*)d_in[10];
  const float* bout = (const float*)d_in[11];
  float* out = (float*)d_out;

  float* ws   = (float*)d_ws;
  float* X0G  = ws;                         // 2560*2048 = 5,242,880
  float* s0a  = X0G + (size_t)2560*NG;
  float* s0b  = s0a + (size_t)B*HB;
  float* s1a  = s0b + (size_t)B*HB;
  float* s1b  = s1a + (size_t)B*HB;
  float* attb = s1b + (size_t)B*HB;
  float* H1   = attb + (size_t)B*H;         // 2560*512

  float* fin0 = out + (size_t)B*S*V;        // final_state layer 0
  float* fin1 = fin0 + (size_t)B*HB;        // final_state layer 1

  k_x0g<<<dim3(16,20),256,0,stream>>>(tok, base, emb, W0, b0, X0G);

  const float* s0prev = init;               // (B,2H) layer 0
  const float* s1prev = init + (size_t)B*HB;
  for (int t = 0; t < S; ++t) {
    float* s0c = (t & 1) ? s0b : s0a;
    float* s1c = (t & 1) ? s1b : s1a;
    k_cell0<<<dim3(16,8),256,0,stream>>>(s0prev, X0G + (size_t)t*B*NG, W0, s0c,
                                         (t==S-1) ? fin0 : nullptr);
    k_att  <<<dim3(16,8),256,0,stream>>>(s0c, Watt, batt, attb);
    k_cell1<<<dim3(16,8),256,0,stream>>>(s0c, attb, s1prev, W1, b1, s1c,
                                         H1 + (size_t)t*B*H,
                                         (t==S-1) ? fin1 : nullptr);
    s0prev = s0c; s1prev = s1c;
  }

  k_logits<<<dim3(79,20),256,0,stream>>>(H1, Wout, bout, out);
}